// Round 2
// baseline (756.795 us; speedup 1.0000x reference)
//
#include <hip/hip_runtime.h>
#include <math.h>

#define NTOK   1000000
#define NFEAT  128
#define NCLUS  64
#define SUBT   32                       // tokens per wave sub-tile (32x32x16 MFMA M)
#define NSUB   (NTOK / SUBT)            // 31250 -- exact, no tail
#define NBLK   768                      // 3 blocks/CU on 256 CUs
#define NWAVE  (NBLK * 4)               // 3072 waves, static stride
#define CPAD   136                      // center row stride in shorts (272 B, 16B-aligned)

typedef __attribute__((ext_vector_type(8)))  short bf16x8;
typedef __attribute__((ext_vector_type(16))) float f32x16;

// fp32 -> bf16 round-to-nearest-even (bit-exact, no API drift risk)
__device__ __forceinline__ unsigned short f2bf(float f) {
    unsigned u = __float_as_uint(f);
    return (unsigned short)((u + 0x7fffu + ((u >> 16) & 1u)) >> 16);
}
__device__ __forceinline__ float bf2f(unsigned short h) {
    return __uint_as_float((unsigned)h << 16);
}

// ---------------------------------------------------------------------------
// Kernel 1: per-wave static work partition. Each wave owns 32-token sub-tiles
// strided by NWAVE. x loaded global->regs directly in MFMA A-fragment layout
// (row = lane&31, k = (lane>>5)*8 + i), split to bf16 hi/lo, bf16x3 MFMA
// (hi*hi + lo*hi + hi*lo, fp32 accum, d2 err ~1e-4 << expected min-gap ~5).
// Centers staged once in LDS as bf16 hi/lo in B-fragment row-major layout.
// No per-tile barriers, no atomics, no x-LDS traffic.
// ---------------------------------------------------------------------------
__global__ __launch_bounds__(256, 3)
void cluster_part_kernel(const float* __restrict__ x, const float* __restrict__ cc,
                         float* __restrict__ pv, int* __restrict__ pi)
{
    __shared__ unsigned short chi[NCLUS][CPAD];   // 17.4 KB
    __shared__ unsigned short clo[NCLUS][CPAD];   // 17.4 KB
    __shared__ float c2s[NCLUS];
    __shared__ float rv[512];                     // 4 waves x 64 lanes x 2 frags
    __shared__ int   ri[512];

    const int tid = threadIdx.x;
    const int l   = tid & 63;     // lane
    const int w   = tid >> 6;     // wave in block
    const int lr  = l & 31;       // mfma row/col
    const int lh  = l >> 5;       // k-half (0: k 0-7, 1: k 8-15 of the 16-step)

    // ---- stage centers (bf16 hi/lo, B-fragment row-major) + c2, once ----
    {
        const int cl = tid >> 2, q = tid & 3;
        const float* src = cc + cl * NFEAT + q * 32;
        float s = 0.f;
        #pragma unroll
        for (int r = 0; r < 8; ++r) {
            float4 v = *(const float4*)(src + r * 4);
            float vv[4] = {v.x, v.y, v.z, v.w};
            #pragma unroll
            for (int e = 0; e < 4; ++e) {
                float f = vv[e];
                unsigned short h  = f2bf(f);
                unsigned short lo = f2bf(f - bf2f(h));
                chi[cl][q * 32 + r * 4 + e] = h;
                clo[cl][q * 32 + r * 4 + e] = lo;
                s = fmaf(f, f, s);                 // c2 from ORIGINAL fp32
            }
        }
        s += __shfl_xor(s, 1);
        s += __shfl_xor(s, 2);
        if (q == 0) c2s[cl] = s;
    }
    __syncthreads();

    const float c2v0 = c2s[lr];
    const float c2v1 = c2s[lr + 32];

    float bestv0 = INFINITY, bestv1 = INFINITY;
    int   besti0 = 0x7fffffff, besti1 = 0x7fffffff;

    const int gw = blockIdx.x * 4 + w;            // global wave id, 0..3071

    // depth-2 software-pipelined loads: 2 x float4 = lane's 8 k-values per kstep
    float4 pfa[2], pfb[2];
    {
        const float* p0 = x + ((long)gw * SUBT + lr) * NFEAT + lh * 8;
        pfa[0] = *(const float4*)(p0);
        pfb[0] = *(const float4*)(p0 + 4);
        pfa[1] = *(const float4*)(p0 + 16);       // kstep 1
        pfb[1] = *(const float4*)(p0 + 20);
    }

    for (int st = gw; st < NSUB; st += NWAVE) {
        f32x16 acc0, acc1;
        #pragma unroll
        for (int i = 0; i < 16; ++i) { acc0[i] = 0.f; acc1[i] = 0.f; }
        float x2p = 0.f;

        #pragma unroll
        for (int ks = 0; ks < 8; ++ks) {
            float4 a = pfa[ks & 1];
            float4 b = pfb[ks & 1];
            // issue loads for kstep ks+2 (crosses into next sub-tile at ks>=6)
            {
                const int ks2 = (ks + 2) & 7;
                const int st2 = (ks < 6) ? st : st + NWAVE;
                if (st2 < NSUB) {                 // wave-uniform guard
                    const float* p2 = x + ((long)st2 * SUBT + lr) * NFEAT + ks2 * 16 + lh * 8;
                    pfa[ks & 1] = *(const float4*)(p2);
                    pfb[ks & 1] = *(const float4*)(p2 + 4);
                }
            }
            // fp32 -> bf16 hi/lo split, x2 partial from ORIGINAL fp32
            float av[8] = {a.x, a.y, a.z, a.w, b.x, b.y, b.z, b.w};
            bf16x8 ahi, alo;
            #pragma unroll
            for (int e = 0; e < 8; ++e) {
                float f = av[e];
                unsigned short h  = f2bf(f);
                unsigned short lo = f2bf(f - bf2f(h));
                ahi[e] = (short)h;
                alo[e] = (short)lo;
                x2p = fmaf(f, f, x2p);
            }
            // B fragments from LDS (clusters 0-31 / 32-63), 16B-aligned b128
            const int ko = ks * 16 + lh * 8;
            bf16x8 bh0 = *(const bf16x8*)&chi[lr][ko];
            bf16x8 bh1 = *(const bf16x8*)&chi[lr + 32][ko];
            bf16x8 bl0 = *(const bf16x8*)&clo[lr][ko];
            bf16x8 bl1 = *(const bf16x8*)&clo[lr + 32][ko];
            // bf16x3: hi*hi + lo*hi + hi*lo, fp32 accumulate
            acc0 = __builtin_amdgcn_mfma_f32_32x32x16_bf16(ahi, bh0, acc0, 0, 0, 0);
            acc1 = __builtin_amdgcn_mfma_f32_32x32x16_bf16(ahi, bh1, acc1, 0, 0, 0);
            acc0 = __builtin_amdgcn_mfma_f32_32x32x16_bf16(alo, bh0, acc0, 0, 0, 0);
            acc1 = __builtin_amdgcn_mfma_f32_32x32x16_bf16(alo, bh1, acc1, 0, 0, 0);
            acc0 = __builtin_amdgcn_mfma_f32_32x32x16_bf16(ahi, bl0, acc0, 0, 0, 0);
            acc1 = __builtin_amdgcn_mfma_f32_32x32x16_bf16(ahi, bl1, acc1, 0, 0, 0);
        }

        // full row sum-of-squares: lanes l and l+32 hold the two k-halves
        const float x2 = x2p + __shfl_xor(x2p, 32);

        // epilogue: C/D layout col=lane&31, row=(reg&3)+8*(reg>>2)+4*(lane>>5)
        const int base = st * SUBT;
        #pragma unroll
        for (int reg = 0; reg < 16; ++reg) {
            const int r    = (reg & 3) + 8 * (reg >> 2) + 4 * lh;
            const float x2r = __shfl(x2, r);      // lanes r and r+32 hold row r's x2
            const int n    = base + r;
            const float d0 = fmaf(-2.f, acc0[reg], x2r + c2v0);
            const float d1 = fmaf(-2.f, acc1[reg], x2r + c2v1);
            if (d0 < bestv0 || (d0 == bestv0 && n < besti0)) { bestv0 = d0; besti0 = n; }
            if (d1 < bestv1 || (d1 == bestv1 && n < besti1)) { bestv1 = d1; besti1 = n; }
        }
    }

    // ---- block reduction: 8 candidates per cluster (2 lanes x 4 waves) ----
    rv[(w * 64 + l) * 2 + 0] = bestv0;  ri[(w * 64 + l) * 2 + 0] = besti0;
    rv[(w * 64 + l) * 2 + 1] = bestv1;  ri[(w * 64 + l) * 2 + 1] = besti1;
    __syncthreads();

    if (tid < NCLUS) {
        const int nf = tid >> 5, p = tid & 31;
        float bv = INFINITY; int bi = 0x7fffffff;
        #pragma unroll
        for (int ww = 0; ww < 4; ++ww) {
            #pragma unroll
            for (int hh = 0; hh < 2; ++hh) {
                const int idx = (ww * 64 + p + hh * 32) * 2 + nf;
                const float v = rv[idx]; const int ii = ri[idx];
                if (v < bv || (v == bv && ii < bi)) { bv = v; bi = ii; }
            }
        }
        pv[(long)blockIdx.x * NCLUS + tid] = bv;
        pi[(long)blockIdx.x * NCLUS + tid] = bi;
    }
}

// ---------------------------------------------------------------------------
// Kernel 2: final reduce over NBLK partials per cluster + gather x[best]
// ---------------------------------------------------------------------------
__global__ __launch_bounds__(256)
void cluster_final_kernel(const float* __restrict__ x,
                          const float* __restrict__ pv, const int* __restrict__ pi,
                          float* __restrict__ out)
{
    const int c   = blockIdx.x;
    const int tid = threadIdx.x;
    __shared__ float sv[256];
    __shared__ int   si[256];

    float bv = INFINITY; int bi = 0x7fffffff;
    for (int b = tid; b < NBLK; b += 256) {
        float v = pv[(long)b * NCLUS + c]; int ii = pi[(long)b * NCLUS + c];
        if (v < bv || (v == bv && ii < bi)) { bv = v; bi = ii; }
    }
    sv[tid] = bv; si[tid] = bi;
    __syncthreads();
    for (int s = 128; s > 0; s >>= 1) {
        if (tid < s) {
            float v = sv[tid + s]; int ii = si[tid + s];
            if (v < sv[tid] || (v == sv[tid] && ii < si[tid])) {
                sv[tid] = v; si[tid] = ii;
            }
        }
        __syncthreads();
    }
    const int best = si[0];
    if (tid < NFEAT) out[c * NFEAT + tid] = x[(long)best * NFEAT + tid];
}

extern "C" void kernel_launch(void* const* d_in, const int* in_sizes, int n_in,
                              void* d_out, int out_size, void* d_ws, size_t ws_size,
                              hipStream_t stream) {
    const float* x  = (const float*)d_in[0];   // (1, 1000000, 128) f32
    const float* cc = (const float*)d_in[1];   // (64, 128) f32
    float* out = (float*)d_out;                // (1, 64, 128) f32

    float* pv = (float*)d_ws;                                          // NBLK*64 f32
    int*   pi = (int*)((char*)d_ws + (size_t)NBLK * NCLUS * sizeof(float));

    cluster_part_kernel<<<NBLK, 256, 0, stream>>>(x, cc, pv, pi);
    cluster_final_kernel<<<NCLUS, 256, 0, stream>>>(x, pv, pi, out);
}